// Round 1
// baseline (215.033 us; speedup 1.0000x reference)
//
#include <hip/hip_runtime.h>

// Int8 fake-quant linear:
//   sx = max|x|/128; qx = clamp(rint(x/sx),-128,127)
//   sw = max|w|/127; qw = clamp(rint(w/sw),-127,127)
//   out = mul * (sx*sw*(qx @ qw^T) + bias)
// Integer accumulation is exact (|acc| <= 128*127*2048 ~ 3.3e7 < 2^31).

typedef int v4i  __attribute__((ext_vector_type(4)));
typedef int v16i __attribute__((ext_vector_type(16)));

#define MDIM 4096
#define NDIM 8192
#define KDIM 2048

typedef __attribute__((address_space(1))) void* gas_ptr;   // global
typedef __attribute__((address_space(3))) void* las_ptr;   // LDS

// ---------------- init: zero the two absmax slots ----------------
__global__ void init_scales(unsigned* s) {
    if (threadIdx.x < 2) s[threadIdx.x] = 0u;
}

// ---------------- absmax reduction (float bits + atomicMax) ----------------
__global__ void absmax_kernel(const float4* __restrict__ in, int n4,
                              unsigned* __restrict__ out) {
    float m = 0.0f;
    for (int i = blockIdx.x * blockDim.x + threadIdx.x; i < n4;
         i += gridDim.x * blockDim.x) {
        float4 v = in[i];
        m = fmaxf(m, fmaxf(fmaxf(fabsf(v.x), fabsf(v.y)),
                           fmaxf(fabsf(v.z), fabsf(v.w))));
    }
#pragma unroll
    for (int off = 32; off > 0; off >>= 1)
        m = fmaxf(m, __shfl_xor(m, off, 64));
    __shared__ float wmax[4];
    if ((threadIdx.x & 63) == 0) wmax[threadIdx.x >> 6] = m;
    __syncthreads();
    if (threadIdx.x == 0) {
        float mm = fmaxf(fmaxf(wmax[0], wmax[1]), fmaxf(wmax[2], wmax[3]));
        atomicMax(out, __float_as_uint(mm));  // bits compare == float compare (>=0)
    }
}

// ---------------- quantize: float4 -> char4 ----------------
__global__ void quant_kernel(const float4* __restrict__ in, char4* __restrict__ out,
                             const unsigned* __restrict__ maxbits, float divisor,
                             float lo, float hi, int n4) {
    // IEEE division to match reference scale semantics exactly
    const float s = __uint_as_float(*maxbits) / divisor;
    for (int i = blockIdx.x * blockDim.x + threadIdx.x; i < n4;
         i += gridDim.x * blockDim.x) {
        float4 v = in[i];
        char4 q;
        q.x = (signed char)(int)fminf(fmaxf(rintf(v.x / s), lo), hi);
        q.y = (signed char)(int)fminf(fmaxf(rintf(v.y / s), lo), hi);
        q.z = (signed char)(int)fminf(fmaxf(rintf(v.z / s), lo), hi);
        q.w = (signed char)(int)fminf(fmaxf(rintf(v.w / s), lo), hi);
        out[i] = q;
    }
}

// ---------------- int8 MFMA GEMM ----------------
// Tile: BM=BN=128, BK=64 bytes of K. 4 waves, each owns a 64x64 quadrant
// (2x2 tiles of mfma_i32_32x32x32_i8). LDS chunk-plane layout:
//   chunk index i in [0,512): plane p = i>>7 (16B K-chunk), row r = i&127
//   byte addr = i*16  (linear -> global_load_lds friendly)
// Frag read: lane l needs row r, chunk c=2s+(l>>5) -> idx c*128 + r
//   bank = 4*(r%8): 8 consecutive rows cover all 32 banks.
__global__ __launch_bounds__(256) void gemm_i8(
    const signed char* __restrict__ qx, const signed char* __restrict__ qw,
    const float* __restrict__ bias, const float* __restrict__ mulv,
    const unsigned* __restrict__ scales, float* __restrict__ out) {
    __shared__ v4i ldsA[2][512];   // 16 KB
    __shared__ v4i ldsB[2][512];   // 16 KB

    const int t    = threadIdx.x;
    const int lane = t & 63;
    const int w    = t >> 6;
    const int wr   = w >> 1;   // quadrant row (0..1)
    const int wc   = w & 1;    // quadrant col (0..1)
    const int bm   = blockIdx.y;
    const int bn   = blockIdx.x;

    // staging source (j=0); j=1 adds +32 bytes (plane+2)
    const signed char* gA = qx + (size_t)(bm * 128 + (t & 127)) * KDIM + (t >> 7) * 16;
    const signed char* gB = qw + (size_t)(bn * 128 + (t & 127)) * KDIM + (t >> 7) * 16;
    const int wave_chunk = w * 64;   // LDS chunk base for this wave (j=0)

    v16i acc[2][2];
#pragma unroll
    for (int m = 0; m < 2; ++m)
#pragma unroll
        for (int n = 0; n < 2; ++n)
#pragma unroll
            for (int r = 0; r < 16; ++r) acc[m][n][r] = 0;

    auto stage = [&](int buf, int kt) {
        const signed char* ga = gA + kt * 64;
        const signed char* gb = gB + kt * 64;
        __builtin_amdgcn_global_load_lds((gas_ptr)ga,
            (las_ptr)&ldsA[buf][wave_chunk], 16, 0, 0);
        __builtin_amdgcn_global_load_lds((gas_ptr)(ga + 32),
            (las_ptr)&ldsA[buf][256 + wave_chunk], 16, 0, 0);
        __builtin_amdgcn_global_load_lds((gas_ptr)gb,
            (las_ptr)&ldsB[buf][wave_chunk], 16, 0, 0);
        __builtin_amdgcn_global_load_lds((gas_ptr)(gb + 32),
            (las_ptr)&ldsB[buf][256 + wave_chunk], 16, 0, 0);
    };

    stage(0, 0);
    __syncthreads();

    int cur = 0;
    const int NT = KDIM / 64;  // 32
    for (int kt = 0; kt < NT; ++kt) {
        if (kt + 1 < NT) stage(cur ^ 1, kt + 1);
        const v4i* A  = &ldsA[cur][0];
        const v4i* Bt = &ldsB[cur][0];
#pragma unroll
        for (int s = 0; s < 2; ++s) {
            const int cbase = (2 * s + (lane >> 5)) * 128 + (lane & 31);
            v4i a0 = A[cbase + wr * 64];
            v4i a1 = A[cbase + wr * 64 + 32];
            v4i b0 = Bt[cbase + wc * 64];
            v4i b1 = Bt[cbase + wc * 64 + 32];
            acc[0][0] = __builtin_amdgcn_mfma_i32_32x32x32_i8(a0, b0, acc[0][0], 0, 0, 0);
            acc[0][1] = __builtin_amdgcn_mfma_i32_32x32x32_i8(a0, b1, acc[0][1], 0, 0, 0);
            acc[1][0] = __builtin_amdgcn_mfma_i32_32x32x32_i8(a1, b0, acc[1][0], 0, 0, 0);
            acc[1][1] = __builtin_amdgcn_mfma_i32_32x32x32_i8(a1, b1, acc[1][1], 0, 0, 0);
        }
        __syncthreads();  // drains vmcnt: stage(kt+1) visible; buf[cur] reads done
        cur ^= 1;
    }

    // epilogue: out = fs*acc + mul*bias ; C/D: col=lane&31, row=(r&3)+8*(r>>2)+4*(lane>>5)
    const float fm = mulv[0];
    const float sx = __uint_as_float(scales[0]) / 128.0f;
    const float sw = __uint_as_float(scales[1]) / 127.0f;
    const float fs = fm * sx * sw;
    const int hi4 = (lane >> 5) * 4;
    const int col = lane & 31;
#pragma unroll
    for (int n = 0; n < 2; ++n) {
        const int ocol = bn * 128 + wc * 64 + n * 32 + col;
        const float bv = bias[ocol] * fm;
#pragma unroll
        for (int m = 0; m < 2; ++m) {
            const int orow0 = bm * 128 + wr * 64 + m * 32;
            float* op = out + (size_t)orow0 * NDIM + ocol;
#pragma unroll
            for (int r = 0; r < 16; ++r) {
                const int row = (r & 3) + 8 * (r >> 2) + hi4;
                op[(size_t)row * NDIM] = fs * (float)acc[m][n][r] + bv;
            }
        }
    }
}

extern "C" void kernel_launch(void* const* d_in, const int* in_sizes, int n_in,
                              void* d_out, int out_size, void* d_ws, size_t ws_size,
                              hipStream_t stream) {
    const float* x    = (const float*)d_in[0];
    const float* wgt  = (const float*)d_in[1];
    const float* bias = (const float*)d_in[2];
    const float* mulv = (const float*)d_in[3];
    float* out = (float*)d_out;

    // workspace layout: [0..8): 2 absmax slots; qx at +256 (8 MB); qw after (16 MB)
    unsigned* scales = (unsigned*)d_ws;
    signed char* qx = (signed char*)d_ws + 256;
    signed char* qw = qx + (size_t)MDIM * KDIM;

    const int nx4 = MDIM * KDIM / 4;  // 2M float4
    const int nw4 = NDIM * KDIM / 4;  // 4M float4

    init_scales<<<1, 64, 0, stream>>>(scales);
    absmax_kernel<<<1024, 256, 0, stream>>>((const float4*)x, nx4, scales + 0);
    absmax_kernel<<<2048, 256, 0, stream>>>((const float4*)wgt, nw4, scales + 1);
    quant_kernel<<<1024, 256, 0, stream>>>((const float4*)x, (char4*)qx,
                                           scales + 0, 128.0f, -128.0f, 127.0f, nx4);
    quant_kernel<<<2048, 256, 0, stream>>>((const float4*)wgt, (char4*)qw,
                                           scales + 1, 127.0f, -127.0f, 127.0f, nw4);

    dim3 grid(NDIM / 128, MDIM / 128);  // 64 x 32 tiles
    gemm_i8<<<grid, 256, 0, stream>>>(qx, qw, bias, mulv, scales, out);
}

// Round 2
// 170.732 us; speedup vs baseline: 1.2595x; 1.2595x over previous
//
#include <hip/hip_runtime.h>

// Int8 fake-quant linear (exact integer accumulation):
//   sx = max|x|/128; qx = clamp(rint(x/sx),-128,127)
//   sw = max|w|/127; qw = clamp(rint(w/sw),-127,127)
//   out = mul * (sx*sw*(qx @ qw^T) + bias)

typedef int v4i  __attribute__((ext_vector_type(4)));
typedef int v16i __attribute__((ext_vector_type(16)));

#define MDIM 4096
#define NDIM 8192
#define KDIM 2048
#define NT   (KDIM / 64)   // 32 K-tiles of BK=64 int8

typedef __attribute__((address_space(1))) void* gas_ptr;   // global
typedef __attribute__((address_space(3))) void* las_ptr;   // LDS

// ---------------- init: zero the two absmax slots ----------------
__global__ void init_scales(unsigned* s) {
    if (threadIdx.x < 2) s[threadIdx.x] = 0u;
}

// ---------------- fused absmax over x and w ----------------
#define XBLK 1024
__global__ void absmax2(const float4* __restrict__ x, int nx4,
                        const float4* __restrict__ w, int nw4,
                        unsigned* __restrict__ out) {
    const bool isx = blockIdx.x < XBLK;
    const float4* in = isx ? x : w;
    const int n4 = isx ? nx4 : nw4;
    const int nb = isx ? XBLK : (gridDim.x - XBLK);
    const int b  = isx ? blockIdx.x : (blockIdx.x - XBLK);
    float m = 0.0f;
    for (int i = b * blockDim.x + threadIdx.x; i < n4; i += nb * blockDim.x) {
        float4 v = in[i];
        m = fmaxf(m, fmaxf(fmaxf(fabsf(v.x), fabsf(v.y)),
                           fmaxf(fabsf(v.z), fabsf(v.w))));
    }
#pragma unroll
    for (int off = 32; off > 0; off >>= 1)
        m = fmaxf(m, __shfl_xor(m, off, 64));
    __shared__ float wm[4];
    if ((threadIdx.x & 63) == 0) wm[threadIdx.x >> 6] = m;
    __syncthreads();
    if (threadIdx.x == 0) {
        float mm = fmaxf(fmaxf(wm[0], wm[1]), fmaxf(wm[2], wm[3]));
        atomicMax(out + (isx ? 0 : 1), __float_as_uint(mm));
    }
}

// ---------------- fused quantize x and w: float4 -> char4 ----------------
__global__ void quant2(const float4* __restrict__ x, char4* __restrict__ qx, int nx4,
                       const float4* __restrict__ w, char4* __restrict__ qw, int nw4,
                       const unsigned* __restrict__ scales) {
    const bool isx = blockIdx.x < XBLK;
    const float4* in = isx ? x : w;
    char4* outq = isx ? qx : qw;
    const int n4 = isx ? nx4 : nw4;
    const int nb = isx ? XBLK : (gridDim.x - XBLK);
    const int b  = isx ? blockIdx.x : (blockIdx.x - XBLK);
    const float s  = __uint_as_float(scales[isx ? 0 : 1]) / (isx ? 128.0f : 127.0f);
    const float lo = isx ? -128.0f : -127.0f;
    const float hi = 127.0f;
    for (int i = b * blockDim.x + threadIdx.x; i < n4; i += nb * blockDim.x) {
        float4 v = in[i];
        char4 q;
        q.x = (signed char)(int)fminf(fmaxf(rintf(v.x / s), lo), hi);
        q.y = (signed char)(int)fminf(fmaxf(rintf(v.y / s), lo), hi);
        q.z = (signed char)(int)fminf(fmaxf(rintf(v.z / s), lo), hi);
        q.w = (signed char)(int)fminf(fmaxf(rintf(v.w / s), lo), hi);
        outq[i] = q;
    }
}

// ---------------- int8 MFMA GEMM, 256x256 tile, 4-deep LDS ring ----------------
// BM=BN=256, BK=64 int8. 8 waves (2M x 4N); each wave owns 128x64 output =
// 4x2 tiles of mfma_i32_32x32x32_i8 (128 acc VGPRs).
// LDS: 4-buffer ring, per buffer A[256 rows][64 B] + B[256][64 B] row-major
// (linear for global_load_lds), total 128 KiB.
// XOR swizzle (both sides, rule 21): LDS[R][j] holds global chunk j^sigma(R),
// sigma(R) = (R>>1)&3 -- pre-swizzled GLOBAL source, swizzled ds_read addr.
// 8 consecutive lanes then cover all 32 banks (conflict-free b128).
// Schedule: per iter {s_waitcnt vmcnt(8); s_barrier; stage tile t+3; 2 k-slices
// of (6 ds_read_b128 -> setprio(1) 8 MFMA setprio(0))}. Loads never drain to 0.
__global__ __launch_bounds__(512, 2) void gemm_i8(
    const signed char* __restrict__ qx, const signed char* __restrict__ qw,
    const float* __restrict__ bias, const float* __restrict__ mulv,
    const unsigned* __restrict__ scales, float* __restrict__ out) {
    __shared__ signed char ldsA[4][16384];
    __shared__ signed char ldsB[4][16384];

    const int t    = threadIdx.x;
    const int lane = t & 63;
    const int w    = t >> 6;      // 0..7
    const int wr   = w >> 2;      // 0..1  (M half)
    const int wc   = w & 3;       // 0..3  (N quarter)

    // XCD-aware swizzle: 512 workgroups, 512 % 8 == 0 -> simple bijection.
    const int orig = blockIdx.x;
    const int wg   = ((orig & 7) << 6) | (orig >> 3);
    const int bm   = wg >> 5;     // 0..15
    const int bn   = wg & 31;     // 0..31

    // ---- staging addresses (pre-swizzled global source, linear LDS dest) ----
    const int r0 = t >> 2;                                // 0..127
    const int sc = ((t & 3) ^ ((r0 >> 1) & 3)) * 16;      // swizzled chunk byte
    const signed char* a0 = qx + (size_t)(bm * 256 + r0) * KDIM + sc;
    const signed char* a1 = a0 + (size_t)128 * KDIM;
    const signed char* b0 = qw + (size_t)(bn * 256 + r0) * KDIM + sc;
    const signed char* b1 = b0 + (size_t)128 * KDIM;
    signed char* dA = &ldsA[0][t * 16];   // wave-uniform base + lane*16 (linear)
    signed char* dB = &ldsB[0][t * 16];

    auto stage = [&](int buf, int kt) {
        const int ko = kt * 64;
        __builtin_amdgcn_global_load_lds((gas_ptr)(a0 + ko), (las_ptr)(dA + buf * 16384),        16, 0, 0);
        __builtin_amdgcn_global_load_lds((gas_ptr)(a1 + ko), (las_ptr)(dA + buf * 16384 + 8192), 16, 0, 0);
        __builtin_amdgcn_global_load_lds((gas_ptr)(b0 + ko), (las_ptr)(dB + buf * 16384),        16, 0, 0);
        __builtin_amdgcn_global_load_lds((gas_ptr)(b1 + ko), (las_ptr)(dB + buf * 16384 + 8192), 16, 0, 0);
    };

    // ---- fragment read addressing ----
    const int hi    = lane >> 5;
    const int sigma = ((lane & 31) >> 1) & 3;
    const int aBase = (wr * 128 + (lane & 31)) * 64;      // + mt*2048 + chunk
    const int bBase = (wc * 64  + (lane & 31)) * 64;      // + nt*2048 + chunk
    const int ck0   = ((0 + hi) ^ sigma) * 16;            // k-slice 0
    const int ck1   = ((2 + hi) ^ sigma) * 16;            // k-slice 1

    v16i acc[4][2];
#pragma unroll
    for (int mt = 0; mt < 4; ++mt)
#pragma unroll
        for (int nt = 0; nt < 2; ++nt)
#pragma unroll
            for (int r = 0; r < 16; ++r) acc[mt][nt][r] = 0;

    auto compute = [&](int buf) {
        const signed char* A = &ldsA[buf][0];
        const signed char* B = &ldsB[buf][0];
#pragma unroll
        for (int s = 0; s < 2; ++s) {
            const int ck = s ? ck1 : ck0;
            v4i a[4], b[2];
#pragma unroll
            for (int mt = 0; mt < 4; ++mt)
                a[mt] = *(const v4i*)(A + aBase + mt * 2048 + ck);
#pragma unroll
            for (int nt = 0; nt < 2; ++nt)
                b[nt] = *(const v4i*)(B + bBase + nt * 2048 + ck);
            __builtin_amdgcn_s_setprio(1);
#pragma unroll
            for (int mt = 0; mt < 4; ++mt)
#pragma unroll
                for (int nt = 0; nt < 2; ++nt)
                    acc[mt][nt] = __builtin_amdgcn_mfma_i32_32x32x32_i8(
                        a[mt], b[nt], acc[mt][nt], 0, 0, 0);
            __builtin_amdgcn_s_setprio(0);
        }
    };

    // ---- prologue: 3 tiles in flight ----
    stage(0, 0);
    stage(1, 1);
    stage(2, 2);

    // ---- main loop: counted vmcnt, one barrier per K-tile ----
    for (int kt = 0; kt < NT - 2; ++kt) {
        asm volatile("s_waitcnt vmcnt(8)" ::: "memory");
        __builtin_amdgcn_s_barrier();
        if (kt < NT - 3) stage((kt + 3) & 3, kt + 3);
        compute(kt & 3);
    }
    asm volatile("s_waitcnt vmcnt(4)" ::: "memory");
    __builtin_amdgcn_s_barrier();
    compute((NT - 2) & 3);
    asm volatile("s_waitcnt vmcnt(0)" ::: "memory");
    __builtin_amdgcn_s_barrier();
    compute((NT - 1) & 3);

    // ---- epilogue: out = fs*acc + mul*bias ----
    // C/D layout (32x32): col = lane&31, row = (r&3) + 8*(r>>2) + 4*(lane>>5)
    const float fm = mulv[0];
    const float fs = fm * (__uint_as_float(scales[0]) / 128.0f)
                        * (__uint_as_float(scales[1]) / 127.0f);
    const int colb = bn * 256 + wc * 64 + (lane & 31);
    const int hi4  = hi * 4;
#pragma unroll
    for (int nt = 0; nt < 2; ++nt) {
        const int ocol = colb + nt * 32;
        const float bv = bias[ocol] * fm;
#pragma unroll
        for (int mt = 0; mt < 4; ++mt) {
            float* op = out + (size_t)(bm * 256 + wr * 128 + mt * 32) * NDIM + ocol;
#pragma unroll
            for (int r = 0; r < 16; ++r) {
                const int row = (r & 3) + 8 * (r >> 2) + hi4;
                op[(size_t)row * NDIM] = fs * (float)acc[mt][nt][r] + bv;
            }
        }
    }
}

extern "C" void kernel_launch(void* const* d_in, const int* in_sizes, int n_in,
                              void* d_out, int out_size, void* d_ws, size_t ws_size,
                              hipStream_t stream) {
    const float* x    = (const float*)d_in[0];
    const float* wgt  = (const float*)d_in[1];
    const float* bias = (const float*)d_in[2];
    const float* mulv = (const float*)d_in[3];
    float* out = (float*)d_out;

    unsigned* scales = (unsigned*)d_ws;
    signed char* qx = (signed char*)d_ws + 256;
    signed char* qw = qx + (size_t)MDIM * KDIM;

    const int nx4 = MDIM * KDIM / 4;  // 2M float4
    const int nw4 = NDIM * KDIM / 4;  // 4M float4

    init_scales<<<1, 64, 0, stream>>>(scales);
    absmax2<<<3072, 256, 0, stream>>>((const float4*)x, nx4,
                                      (const float4*)wgt, nw4, scales);
    quant2<<<3072, 256, 0, stream>>>((const float4*)x, (char4*)qx, nx4,
                                     (const float4*)wgt, (char4*)qw, nw4, scales);

    gemm_i8<<<512, 512, 0, stream>>>(qx, qw, bias, mulv, scales, out);
}